// Round 1
// baseline (1001.790 us; speedup 1.0000x reference)
//
#include <hip/hip_runtime.h>
#include <hip/hip_bf16.h>
#include <math.h>

// Problem constants (fixed by reference setup_inputs)
#define N_TOK 8192   // B*S = 4*2048
#define DIM   1024   // D
#define HID   4096   // H
#define NEXP  8      // E
#define CAP   2048   // ceil(1.0 * 2 * 8192 / 8)

typedef short bf16x8 __attribute__((ext_vector_type(8)));
typedef float f32x4  __attribute__((ext_vector_type(4)));

__device__ __forceinline__ unsigned short f2bf(float f) {
    union { float f; unsigned u; } v; v.f = f;
    unsigned r = v.u;
    unsigned lsb = (r >> 16) & 1u;
    r += 0x7fffu + lsb;          // round-to-nearest-even on bf16 boundary
    return (unsigned short)(r >> 16);
}

// ---------------------------------------------------------------------------
// init: zero out[] (atomic combine target), invalidate slot map
// ---------------------------------------------------------------------------
__global__ __launch_bounds__(256) void init_kernel(float* __restrict__ out,
                                                   int* __restrict__ slot_token,
                                                   float* __restrict__ slot_gate) {
    int gid = blockIdx.x * 256 + threadIdx.x;     // 8192*256 threads, 1 float4 each
    f32x4 z = {0.f, 0.f, 0.f, 0.f};
    *(f32x4*)(out + (size_t)gid * 4) = z;
    if (gid < NEXP * CAP) { slot_token[gid] = -1; slot_gate[gid] = 0.f; }
}

// ---------------------------------------------------------------------------
// transpose + fp32->bf16 convert:  in fp32 [E][R][C]  ->  out bf16 [E][C][R]
// ---------------------------------------------------------------------------
__global__ __launch_bounds__(256) void transpose_convert_kernel(
        const float* __restrict__ in, unsigned short* __restrict__ outp,
        int R, int C) {
    int e  = blockIdx.z;
    int c0 = blockIdx.x * 32, r0 = blockIdx.y * 32;
    __shared__ float tile[32][33];                // +1 pad: conflict-free
    const float* ip = in + (size_t)e * R * C;
    unsigned short* op = outp + (size_t)e * R * C;
    int t = threadIdx.x;
    int tc = t & 31, tr = t >> 5;                 // 8 rows per phase
    #pragma unroll
    for (int p = 0; p < 4; ++p) {
        int r = tr + p * 8;
        tile[r][tc] = ip[(size_t)(r0 + r) * C + c0 + tc];   // coalesced read
    }
    __syncthreads();
    #pragma unroll
    for (int p = 0; p < 4; ++p) {
        int c = tr + p * 8;                       // output row = c0+c
        op[(size_t)(c0 + c) * R + r0 + tc] = f2bf(tile[tc][c]);  // coalesced write
    }
}

// ---------------------------------------------------------------------------
// gate: one wave per token. fp32 logits, softmax, top-2, normalized gates.
// ---------------------------------------------------------------------------
__global__ __launch_bounds__(256) void gate_kernel(
        const float* __restrict__ x, const float* __restrict__ wg,
        int* __restrict__ tok_e, float* __restrict__ tok_g) {
    int wave = threadIdx.x >> 6, lane = threadIdx.x & 63;
    int n = blockIdx.x * 4 + wave;
    const float* xr = x + (size_t)n * DIM;
    float acc[8];
    #pragma unroll
    for (int e = 0; e < 8; ++e) acc[e] = 0.f;
    for (int j = 0; j < DIM / 64; ++j) {
        int d = lane + 64 * j;
        float xv = xr[d];
        const f32x4* wr = (const f32x4*)(wg + (size_t)d * 8);
        f32x4 w0 = wr[0], w1 = wr[1];
        acc[0] += xv * w0[0]; acc[1] += xv * w0[1];
        acc[2] += xv * w0[2]; acc[3] += xv * w0[3];
        acc[4] += xv * w1[0]; acc[5] += xv * w1[1];
        acc[6] += xv * w1[2]; acc[7] += xv * w1[3];
    }
    #pragma unroll
    for (int off = 32; off > 0; off >>= 1) {
        #pragma unroll
        for (int e = 0; e < 8; ++e) acc[e] += __shfl_down(acc[e], off);
    }
    if (lane == 0) {
        float mx = acc[0];
        #pragma unroll
        for (int e = 1; e < 8; ++e) mx = fmaxf(mx, acc[e]);
        float p[8], s = 0.f;
        #pragma unroll
        for (int e = 0; e < 8; ++e) { p[e] = expf(acc[e] - mx); s += p[e]; }
        int i0 = 0;
        #pragma unroll
        for (int e = 1; e < 8; ++e) if (acc[e] > acc[i0]) i0 = e;   // ties -> lowest idx
        int i1 = (i0 == 0) ? 1 : 0;
        #pragma unroll
        for (int e = 0; e < 8; ++e) if (e != i0 && acc[e] > acc[i1]) i1 = e;
        float g0 = p[i0] / s, g1 = p[i1] / s;
        float gs = fmaxf(g0 + g1, 1e-9f);
        tok_e[n * 2 + 0] = i0;  tok_e[n * 2 + 1] = i1;
        tok_g[n * 2 + 0] = g0 / gs;  tok_g[n * 2 + 1] = g1 / gs;
    }
}

// ---------------------------------------------------------------------------
// route: GShard capacity positions. 1 block, 8 waves; wave w owns expert w.
// Sequential over token order via ballots; counts carry k=0 -> k=1 (= offset).
// ---------------------------------------------------------------------------
__global__ __launch_bounds__(512) void route_kernel(
        const int* __restrict__ tok_e, const float* __restrict__ tok_g,
        int* __restrict__ slot_token, float* __restrict__ slot_gate) {
    int w = threadIdx.x >> 6;      // expert id
    int lane = threadIdx.x & 63;
    unsigned long long below = (lane == 63) ? 0x7fffffffffffffffull
                                            : ((1ull << lane) - 1ull);
    int cnt = 0;
    for (int kk = 0; kk < 2; ++kk) {
        for (int base = 0; base < N_TOK; base += 64) {
            int n = base + lane;
            int ei = tok_e[n * 2 + kk];
            bool mine = (ei == w);
            unsigned long long m = __ballot(mine);
            if (mine) {
                int pos = cnt + __popcll(m & below);
                if (pos < CAP) {
                    slot_token[w * CAP + pos] = n;
                    slot_gate[w * CAP + pos]  = tok_g[n * 2 + kk];
                }
            }
            cnt += __popcll(m);
        }
    }
}

// ---------------------------------------------------------------------------
// dispatch: gather token rows into bf16 disp[E*CAP][DIM]; zero empty slots
// ---------------------------------------------------------------------------
__global__ __launch_bounds__(256) void dispatch_kernel(
        const float* __restrict__ x, const int* __restrict__ slot_token,
        unsigned short* __restrict__ disp) {
    int s = blockIdx.x;
    int tok = slot_token[s];
    int t = threadIdx.x;
    unsigned short* dp = disp + (size_t)s * DIM + t * 4;
    uint2 o;
    if (tok < 0) { o.x = 0u; o.y = 0u; }
    else {
        const f32x4 v = *(const f32x4*)(x + (size_t)tok * DIM + t * 4);
        o.x = (unsigned)f2bf(v[0]) | ((unsigned)f2bf(v[1]) << 16);
        o.y = (unsigned)f2bf(v[2]) | ((unsigned)f2bf(v[3]) << 16);
    }
    *(uint2*)dp = o;
}

// ---------------------------------------------------------------------------
// GEMM core (m97 structure): 128x128 tile, 4 waves (2x2), BK=32,
// 16x16x32 bf16 MFMA, width-16 global_load_lds staging, 2 barriers/K-step.
// A: [..][KD] row-major bf16, B: [..][KD] row-major bf16 (i.e. B^T layout).
// ---------------------------------------------------------------------------
template<int KD>
__device__ __forceinline__ void gemm_mainloop(
        const unsigned short* __restrict__ A, const unsigned short* __restrict__ B,
        unsigned short* lsA, unsigned short* lsB, f32x4 (&acc)[4][4]) {
    const int t = threadIdx.x;
    const int wave = t >> 6, lane = t & 63;
    const int lane16 = lane & 15, kh = lane >> 4;
    const int wm = wave >> 1, wn = wave & 1;

    for (int k0 = 0; k0 < KD; k0 += 32) {
        #pragma unroll
        for (int i = 0; i < 2; ++i) {
            const int lin = i * 2048 + wave * 512;   // wave-uniform elem offset
            const int el  = lin + lane * 8;          // this lane's 8 elements
            const int r   = el >> 5, c = el & 31;
            __builtin_amdgcn_global_load_lds(
                (const __attribute__((address_space(1))) void*)(A + (size_t)r * KD + k0 + c),
                (__attribute__((address_space(3))) void*)(lsA + lin), 16, 0, 0);
            __builtin_amdgcn_global_load_lds(
                (const __attribute__((address_space(1))) void*)(B + (size_t)r * KD + k0 + c),
                (__attribute__((address_space(3))) void*)(lsB + lin), 16, 0, 0);
        }
        __syncthreads();   // compiler emits vmcnt(0) drain -> LDS tiles ready
        bf16x8 af[4], bfr[4];
        #pragma unroll
        for (int m = 0; m < 4; ++m)
            af[m] = *(const bf16x8*)(lsA + (wm * 64 + m * 16 + lane16) * 32 + kh * 8);
        #pragma unroll
        for (int n = 0; n < 4; ++n)
            bfr[n] = *(const bf16x8*)(lsB + (wn * 64 + n * 16 + lane16) * 32 + kh * 8);
        #pragma unroll
        for (int m = 0; m < 4; ++m)
            #pragma unroll
            for (int n = 0; n < 4; ++n)
                acc[m][n] = __builtin_amdgcn_mfma_f32_16x16x32_bf16(af[m], bfr[n], acc[m][n], 0, 0, 0);
        __syncthreads();   // protect LDS before next stage
    }
}

// GEMM1: h[e] = gelu(disp[e] @ w1[e] + b1[e]),  M=CAP, N=HID, K=DIM
__global__ __launch_bounds__(256) void gemm1_kernel(
        const unsigned short* __restrict__ disp, const unsigned short* __restrict__ w1t,
        const float* __restrict__ b1, unsigned short* __restrict__ h) {
    const int e = blockIdx.y;
    const int TN = HID / 128;   // 32
    const int tm = blockIdx.x / TN, tn = blockIdx.x % TN;
    __shared__ unsigned short lsA[128 * 32];
    __shared__ unsigned short lsB[128 * 32];
    const unsigned short* A = disp + (size_t)e * CAP * DIM + (size_t)tm * 128 * DIM;
    const unsigned short* B = w1t  + (size_t)e * HID * DIM + (size_t)tn * 128 * DIM;
    f32x4 acc[4][4];
    #pragma unroll
    for (int m = 0; m < 4; ++m)
        #pragma unroll
        for (int n = 0; n < 4; ++n) acc[m][n] = (f32x4){0.f, 0.f, 0.f, 0.f};

    gemm_mainloop<DIM>(A, B, lsA, lsB, acc);

    const int lane = threadIdx.x & 63, wave = threadIdx.x >> 6;
    const int lane16 = lane & 15, kh = lane >> 4;
    const int wm = wave >> 1, wn = wave & 1;
    const float* b1e = b1 + (size_t)e * HID + tn * 128;
    unsigned short* H = h + (size_t)e * CAP * HID + (size_t)(tm * 128) * HID + tn * 128;
    #pragma unroll
    for (int m = 0; m < 4; ++m)
        #pragma unroll
        for (int n = 0; n < 4; ++n)
            #pragma unroll
            for (int r = 0; r < 4; ++r) {
                int row = wm * 64 + m * 16 + kh * 4 + r;   // C/D: row=(lane>>4)*4+reg
                int col = wn * 64 + n * 16 + lane16;       //      col=lane&15
                float v = acc[m][n][r] + b1e[col];
                v = 0.5f * v * (1.0f + erff(v * 0.70710678118654752f));  // exact GELU
                H[(size_t)row * HID + col] = f2bf(v);
            }
}

// GEMM2: y[e] = h[e] @ w2[e] + b2[e]; combine fused via gate-weighted atomicAdd
__global__ __launch_bounds__(256) void gemm2_kernel(
        const unsigned short* __restrict__ h, const unsigned short* __restrict__ w2t,
        const float* __restrict__ b2, const int* __restrict__ slot_token,
        const float* __restrict__ slot_gate, float* __restrict__ out) {
    const int e = blockIdx.y;
    const int TN = DIM / 128;   // 8
    const int tm = blockIdx.x / TN, tn = blockIdx.x % TN;
    __shared__ unsigned short lsA[128 * 32];
    __shared__ unsigned short lsB[128 * 32];
    const unsigned short* A = h   + (size_t)e * CAP * HID + (size_t)tm * 128 * HID;
    const unsigned short* B = w2t + (size_t)e * DIM * HID + (size_t)tn * 128 * HID;
    f32x4 acc[4][4];
    #pragma unroll
    for (int m = 0; m < 4; ++m)
        #pragma unroll
        for (int n = 0; n < 4; ++n) acc[m][n] = (f32x4){0.f, 0.f, 0.f, 0.f};

    gemm_mainloop<HID>(A, B, lsA, lsB, acc);

    const int lane = threadIdx.x & 63, wave = threadIdx.x >> 6;
    const int lane16 = lane & 15, kh = lane >> 4;
    const int wm = wave >> 1, wn = wave & 1;
    const float* b2e = b2 + (size_t)e * DIM + tn * 128;
    #pragma unroll
    for (int m = 0; m < 4; ++m)
        #pragma unroll
        for (int r = 0; r < 4; ++r) {
            int row = wm * 64 + m * 16 + kh * 4 + r;
            int slot = e * CAP + tm * 128 + row;
            int tok = slot_token[slot];
            if (tok >= 0) {
                float g = slot_gate[slot];
                #pragma unroll
                for (int n = 0; n < 4; ++n) {
                    int col = wn * 64 + n * 16 + lane16;
                    float v = acc[m][n][r] + b2e[col];
                    atomicAdd(out + (size_t)tok * DIM + tn * 128 + col, v * g);
                }
            }
        }
}

// ---------------------------------------------------------------------------
extern "C" void kernel_launch(void* const* d_in, const int* in_sizes, int n_in,
                              void* d_out, int out_size, void* d_ws, size_t ws_size,
                              hipStream_t stream) {
    (void)in_sizes; (void)n_in; (void)out_size; (void)ws_size;
    const float* x  = (const float*)d_in[0];
    const float* wg = (const float*)d_in[1];
    const float* w1 = (const float*)d_in[2];
    const float* b1 = (const float*)d_in[3];
    const float* w2 = (const float*)d_in[4];
    const float* b2 = (const float*)d_in[5];
    float* out = (float*)d_out;

    char* ws = (char*)d_ws;
    size_t off = 0;
    unsigned short* w1t  = (unsigned short*)(ws + off); off += (size_t)NEXP * HID * DIM * 2;  // 64 MB
    unsigned short* w2t  = (unsigned short*)(ws + off); off += (size_t)NEXP * DIM * HID * 2;  // 64 MB
    unsigned short* disp = (unsigned short*)(ws + off); off += (size_t)NEXP * CAP * DIM * 2;  // 32 MB
    unsigned short* hbuf = (unsigned short*)(ws + off); off += (size_t)NEXP * CAP * HID * 2;  // 128 MB
    int*   slot_token = (int*)  (ws + off); off += (size_t)NEXP * CAP * 4;
    float* slot_gate  = (float*)(ws + off); off += (size_t)NEXP * CAP * 4;
    int*   tok_e      = (int*)  (ws + off); off += (size_t)N_TOK * 2 * 4;
    float* tok_g      = (float*)(ws + off); off += (size_t)N_TOK * 2 * 4;

    hipLaunchKernelGGL(init_kernel, dim3(N_TOK * DIM / 4 / 256), dim3(256), 0, stream,
                       out, slot_token, slot_gate);
    hipLaunchKernelGGL(transpose_convert_kernel, dim3(HID / 32, DIM / 32, NEXP), dim3(256), 0, stream,
                       w1, w1t, DIM, HID);
    hipLaunchKernelGGL(transpose_convert_kernel, dim3(DIM / 32, HID / 32, NEXP), dim3(256), 0, stream,
                       w2, w2t, HID, DIM);
    hipLaunchKernelGGL(gate_kernel, dim3(N_TOK / 4), dim3(256), 0, stream, x, wg, tok_e, tok_g);
    hipLaunchKernelGGL(route_kernel, dim3(1), dim3(512), 0, stream,
                       tok_e, tok_g, slot_token, slot_gate);
    hipLaunchKernelGGL(dispatch_kernel, dim3(NEXP * CAP), dim3(256), 0, stream,
                       x, slot_token, disp);
    hipLaunchKernelGGL(gemm1_kernel, dim3((CAP / 128) * (HID / 128), NEXP), dim3(256), 0, stream,
                       disp, w1t, b1, hbuf);
    hipLaunchKernelGGL(gemm2_kernel, dim3((CAP / 128) * (DIM / 128), NEXP), dim3(256), 0, stream,
                       hbuf, w2t, b2, slot_token, slot_gate, out);
}

// Round 2
// 821.032 us; speedup vs baseline: 1.2202x; 1.2202x over previous
//
#include <hip/hip_runtime.h>
#include <hip/hip_bf16.h>
#include <math.h>

// Problem constants (fixed by reference setup_inputs)
#define N_TOK 8192   // B*S = 4*2048
#define DIM   1024   // D
#define HID   4096   // H
#define NEXP  8      // E
#define CAP   2048   // ceil(1.0 * 2 * 8192 / 8)

typedef short bf16x8 __attribute__((ext_vector_type(8)));
typedef float f32x4  __attribute__((ext_vector_type(4)));

__device__ __forceinline__ unsigned short f2bf(float f) {
    union { float f; unsigned u; } v; v.f = f;
    unsigned r = v.u;
    unsigned lsb = (r >> 16) & 1u;
    r += 0x7fffu + lsb;          // round-to-nearest-even on bf16 boundary
    return (unsigned short)(r >> 16);
}

// ---------------------------------------------------------------------------
// init: zero out[] (atomic combine target), invalidate slot map
// ---------------------------------------------------------------------------
__global__ __launch_bounds__(256) void init_kernel(float* __restrict__ out,
                                                   int* __restrict__ slot_token,
                                                   float* __restrict__ slot_gate) {
    int gid = blockIdx.x * 256 + threadIdx.x;
    f32x4 z = {0.f, 0.f, 0.f, 0.f};
    *(f32x4*)(out + (size_t)gid * 4) = z;
    if (gid < NEXP * CAP) { slot_token[gid] = -1; slot_gate[gid] = 0.f; }
}

// ---------------------------------------------------------------------------
// transpose + fp32->bf16 convert:  in fp32 [E][R][C]  ->  out bf16 [E][C][R]
// ---------------------------------------------------------------------------
__global__ __launch_bounds__(256) void transpose_convert_kernel(
        const float* __restrict__ in, unsigned short* __restrict__ outp,
        int R, int C) {
    int e  = blockIdx.z;
    int c0 = blockIdx.x * 32, r0 = blockIdx.y * 32;
    __shared__ float tile[32][33];
    const float* ip = in + (size_t)e * R * C;
    unsigned short* op = outp + (size_t)e * R * C;
    int t = threadIdx.x;
    int tc = t & 31, tr = t >> 5;
    #pragma unroll
    for (int p = 0; p < 4; ++p) {
        int r = tr + p * 8;
        tile[r][tc] = ip[(size_t)(r0 + r) * C + c0 + tc];
    }
    __syncthreads();
    #pragma unroll
    for (int p = 0; p < 4; ++p) {
        int c = tr + p * 8;
        op[(size_t)(c0 + c) * R + r0 + tc] = f2bf(tile[tc][c]);
    }
}

// ---------------------------------------------------------------------------
// gate: one wave per token. fp32 logits, softmax, top-2, normalized gates.
// ---------------------------------------------------------------------------
__global__ __launch_bounds__(256) void gate_kernel(
        const float* __restrict__ x, const float* __restrict__ wg,
        int* __restrict__ tok_e, float* __restrict__ tok_g) {
    int wave = threadIdx.x >> 6, lane = threadIdx.x & 63;
    int n = blockIdx.x * 4 + wave;
    const float* xr = x + (size_t)n * DIM;
    float acc[8];
    #pragma unroll
    for (int e = 0; e < 8; ++e) acc[e] = 0.f;
    for (int j = 0; j < DIM / 64; ++j) {
        int d = lane + 64 * j;
        float xv = xr[d];
        const f32x4* wr = (const f32x4*)(wg + (size_t)d * 8);
        f32x4 w0 = wr[0], w1 = wr[1];
        acc[0] += xv * w0[0]; acc[1] += xv * w0[1];
        acc[2] += xv * w0[2]; acc[3] += xv * w0[3];
        acc[4] += xv * w1[0]; acc[5] += xv * w1[1];
        acc[6] += xv * w1[2]; acc[7] += xv * w1[3];
    }
    #pragma unroll
    for (int off = 32; off > 0; off >>= 1) {
        #pragma unroll
        for (int e = 0; e < 8; ++e) acc[e] += __shfl_down(acc[e], off);
    }
    if (lane == 0) {
        float mx = acc[0];
        #pragma unroll
        for (int e = 1; e < 8; ++e) mx = fmaxf(mx, acc[e]);
        float p[8], s = 0.f;
        #pragma unroll
        for (int e = 0; e < 8; ++e) { p[e] = expf(acc[e] - mx); s += p[e]; }
        int i0 = 0;
        #pragma unroll
        for (int e = 1; e < 8; ++e) if (acc[e] > acc[i0]) i0 = e;
        int i1 = (i0 == 0) ? 1 : 0;
        #pragma unroll
        for (int e = 0; e < 8; ++e) if (e != i0 && acc[e] > acc[i1]) i1 = e;
        float g0 = p[i0] / s, g1 = p[i1] / s;
        float gs = fmaxf(g0 + g1, 1e-9f);
        tok_e[n * 2 + 0] = i0;  tok_e[n * 2 + 1] = i1;
        tok_g[n * 2 + 0] = g0 / gs;  tok_g[n * 2 + 1] = g1 / gs;
    }
}

// ---------------------------------------------------------------------------
// route: GShard capacity positions. 1 block, 8 waves; wave w owns expert w.
// LDS-staged tok_e so the ballot scan reads LDS, not serial global loads.
// ---------------------------------------------------------------------------
__global__ __launch_bounds__(512) void route_kernel(
        const int* __restrict__ tok_e, const float* __restrict__ tok_g,
        int* __restrict__ slot_token, float* __restrict__ slot_gate) {
    __shared__ int te[N_TOK];      // 32 KB
    int w = threadIdx.x >> 6;      // expert id
    int lane = threadIdx.x & 63;
    unsigned long long below = (lane == 63) ? 0x7fffffffffffffffull
                                            : ((1ull << lane) - 1ull);
    int cnt = 0;
    for (int kk = 0; kk < 2; ++kk) {
        __syncthreads();
        for (int i = threadIdx.x; i < N_TOK; i += 512) te[i] = tok_e[i * 2 + kk];
        __syncthreads();
        #pragma unroll 4
        for (int base = 0; base < N_TOK; base += 64) {
            int n = base + lane;
            bool mine = (te[n] == w);
            unsigned long long m = __ballot(mine);
            if (mine) {
                int pos = cnt + __popcll(m & below);
                if (pos < CAP) {
                    slot_token[w * CAP + pos] = n;
                    slot_gate[w * CAP + pos]  = tok_g[n * 2 + kk];
                }
            }
            cnt += __popcll(m);
        }
    }
}

// ---------------------------------------------------------------------------
// dispatch: gather token rows into bf16 disp[E*CAP][DIM]; zero empty slots
// ---------------------------------------------------------------------------
__global__ __launch_bounds__(256) void dispatch_kernel(
        const float* __restrict__ x, const int* __restrict__ slot_token,
        unsigned short* __restrict__ disp) {
    int s = blockIdx.x;
    int tok = slot_token[s];
    int t = threadIdx.x;
    unsigned short* dp = disp + (size_t)s * DIM + t * 4;
    uint2 o;
    if (tok < 0) { o.x = 0u; o.y = 0u; }
    else {
        const f32x4 v = *(const f32x4*)(x + (size_t)tok * DIM + t * 4);
        o.x = (unsigned)f2bf(v[0]) | ((unsigned)f2bf(v[1]) << 16);
        o.y = (unsigned)f2bf(v[2]) | ((unsigned)f2bf(v[3]) << 16);
    }
    *(uint2*)dp = o;
}

// ---------------------------------------------------------------------------
// 256x256 8-phase GEMM core (T2+T3+T4+T5):
//   BM=BN=256, BK=64, 512 threads = 8 waves (2M x 4N), per-wave C = 128x64.
//   LDS 128 KiB: 2 dbuf x (A,B) x [2 k-halves][16 stripes][64 slots][8 elem].
//   Stripe-transposed layout: slot = c*16 + (row&15)  ->  MFMA frag ds_read is
//   lane-linear (addr = base + lane*16B): ZERO bank conflicts. Inverse
//   permutation applied on the per-lane GLOBAL source address (m173 pattern).
//   Counted vmcnt(4) twice per K-tile (never 0 mid-loop); 2 barriers/K-tile;
//   setprio(1) around each 16-MFMA cluster.
//   A: [M][KD] row-major bf16, B: [N][KD] row-major bf16 (B^T layout).
// ---------------------------------------------------------------------------
template<int KD>
__device__ __forceinline__ void mainloop256(
        const unsigned short* __restrict__ Ag, const unsigned short* __restrict__ Bg,
        unsigned short* lds, f32x4 (&acc)[8][4]) {
    const int t = threadIdx.x;
    const int w = t >> 6, l = t & 63;
    const int wm = w >> 2, wn = w & 3;

    // staging decode: 16B slot s -> logical (row, chunk) of a 256x32 k-half
    const int slot0 = w * 64 + l;
    const int slot1 = 512 + w * 64 + l;
    const int r0 = (slot0 >> 6) * 16 + (slot0 & 15), c0 = (slot0 >> 4) & 3;
    const int r1 = (slot1 >> 6) * 16 + (slot1 & 15), c1 = (slot1 >> 4) & 3;
    const size_t ofs0 = (size_t)r0 * KD + c0 * 8;
    const size_t ofs1 = (size_t)r1 * KD + c1 * 8;
    const int dst0 = (w * 64) * 8;          // wave-uniform LDS elem base, load 0
    const int dst1 = (512 + w * 64) * 8;    // load 1

    auto stage = [&](const unsigned short* G, int ldsbase, int kh, int kt) {
        __builtin_amdgcn_global_load_lds(
            (const __attribute__((address_space(1))) void*)(G + ofs0 + kt + kh * 32),
            (__attribute__((address_space(3))) void*)(lds + ldsbase + kh * 8192 + dst0), 16, 0, 0);
        __builtin_amdgcn_global_load_lds(
            (const __attribute__((address_space(1))) void*)(G + ofs1 + kt + kh * 32),
            (__attribute__((address_space(3))) void*)(lds + ldsbase + kh * 8192 + dst1), 16, 0, 0);
    };
    auto ldA = [&](int abase, int ks, int m) {
        return *(const bf16x8*)(lds + abase + ks * 8192 + (wm * 8 + m) * 512 + l * 8);
    };
    auto ldB = [&](int bbase, int ks, int n) {
        return *(const bf16x8*)(lds + bbase + ks * 8192 + (wn * 4 + n) * 512 + l * 8);
    };

#define MFMA_PAIR(nlo)                                                                     \
    __builtin_amdgcn_s_setprio(1);                                                         \
    _Pragma("unroll")                                                                      \
    for (int m = 0; m < 8; ++m) {                                                          \
        acc[m][nlo]     = __builtin_amdgcn_mfma_f32_16x16x32_bf16(af[m], bf[nlo],     acc[m][nlo],     0, 0, 0); \
        acc[m][nlo + 1] = __builtin_amdgcn_mfma_f32_16x16x32_bf16(af[m], bf[nlo + 1], acc[m][nlo + 1], 0, 0, 0); \
    }                                                                                      \
    __builtin_amdgcn_s_setprio(0);

    constexpr int NT = KD / 64;
    bf16x8 af[8], bf[4];

    // prologue: K-tile 0, issue order A0,B0,A1,B1 (matches steady-state order)
    stage(Ag, 0, 0, 0);  stage(Bg, 16384, 0, 0);
    stage(Ag, 0, 1, 0);  stage(Bg, 16384, 1, 0);

    int cur = 0;
#pragma unroll 1
    for (int T = 0; T < NT; ++T, cur ^= 1) {
        const int abase = cur * 32768, bbase = abase + 16384;
        const int nA = (cur ^ 1) * 32768, nB = nA + 16384;
        const int ktn = (T + 1) * 64;
        const bool pf = (T + 1 < NT);

        // -------- phase 0: A-half0 + B-half0 resident after this wait --------
        asm volatile("s_waitcnt vmcnt(4)\n\ts_barrier" ::: "memory");
        #pragma unroll
        for (int m = 0; m < 8; ++m) af[m] = ldA(abase, 0, m);
        bf[0] = ldB(bbase, 0, 0);  bf[1] = ldB(bbase, 0, 1);
        if (pf) stage(Ag, nA, 0, ktn);
        MFMA_PAIR(0)
        // -------- phase 1 --------
        bf[2] = ldB(bbase, 0, 2);  bf[3] = ldB(bbase, 0, 3);
        if (pf) stage(Bg, nB, 0, ktn);
        MFMA_PAIR(2)
        // -------- phase 2: A-half1 + B-half1 resident after this wait --------
        if (pf) { asm volatile("s_waitcnt vmcnt(4)\n\ts_barrier" ::: "memory"); }
        else    { asm volatile("s_waitcnt vmcnt(0)\n\ts_barrier" ::: "memory"); }
        #pragma unroll
        for (int m = 0; m < 8; ++m) af[m] = ldA(abase, 1, m);
        bf[0] = ldB(bbase, 1, 0);  bf[1] = ldB(bbase, 1, 1);
        if (pf) stage(Ag, nA, 1, ktn);
        MFMA_PAIR(0)
        // -------- phase 3 --------
        bf[2] = ldB(bbase, 1, 2);  bf[3] = ldB(bbase, 1, 3);
        if (pf) stage(Bg, nB, 1, ktn);
        MFMA_PAIR(2)
    }
#undef MFMA_PAIR
}

// GEMM1: h[e] = gelu(disp[e] @ w1[e] + b1[e]),  M=CAP, N=HID, K=DIM
__global__ __launch_bounds__(512, 2) void gemm1_kernel(
        const unsigned short* __restrict__ disp, const unsigned short* __restrict__ w1t,
        const float* __restrict__ b1, unsigned short* __restrict__ h) {
    extern __shared__ unsigned short lds[];
    constexpr int TOT = (CAP / 256) * (HID / 256) * NEXP;   // 1024
    constexpr int TPE = (CAP / 256) * (HID / 256);          // 128
    constexpr int TN  = HID / 256;                          // 16
    const int bid = (blockIdx.x & 7) * (TOT >> 3) + (blockIdx.x >> 3);  // XCD swizzle
    const int e = bid / TPE, tt = bid % TPE, tm = tt / TN, tn = tt % TN;

    const unsigned short* A = disp + ((size_t)e * CAP + tm * 256) * DIM;
    const unsigned short* B = w1t  + ((size_t)e * HID + tn * 256) * DIM;
    f32x4 acc[8][4];
    #pragma unroll
    for (int m = 0; m < 8; ++m)
        #pragma unroll
        for (int n = 0; n < 4; ++n) acc[m][n] = (f32x4){0.f, 0.f, 0.f, 0.f};

    mainloop256<DIM>(A, B, lds, acc);

    const int l = threadIdx.x & 63, w = threadIdx.x >> 6;
    const int l16 = l & 15, kh4 = l >> 4;
    const int wm = w >> 2, wn = w & 3;
    const float* b1e = b1 + (size_t)e * HID + tn * 256;
    float bias[4];
    #pragma unroll
    for (int n = 0; n < 4; ++n) bias[n] = b1e[wn * 64 + n * 16 + l16];
    unsigned short* H = h + ((size_t)e * CAP + tm * 256) * HID + tn * 256;
    #pragma unroll
    for (int m = 0; m < 8; ++m)
        #pragma unroll
        for (int n = 0; n < 4; ++n)
            #pragma unroll
            for (int r = 0; r < 4; ++r) {
                int row = wm * 128 + m * 16 + kh4 * 4 + r;   // C/D: row=(lane>>4)*4+reg
                int col = wn * 64 + n * 16 + l16;            //      col=lane&15
                float v = acc[m][n][r] + bias[n];
                v = 0.5f * v * (1.0f + erff(v * 0.70710678118654752f));  // exact GELU
                H[(size_t)row * HID + col] = f2bf(v);
            }
}

// GEMM2: y[e] = h[e] @ w2[e] + b2[e]; combine fused via gate-weighted atomicAdd
__global__ __launch_bounds__(512, 2) void gemm2_kernel(
        const unsigned short* __restrict__ h, const unsigned short* __restrict__ w2t,
        const float* __restrict__ b2, const int* __restrict__ slot_token,
        const float* __restrict__ slot_gate, float* __restrict__ out) {
    extern __shared__ unsigned short lds[];
    constexpr int TOT = (CAP / 256) * (DIM / 256) * NEXP;   // 256
    constexpr int TPE = (CAP / 256) * (DIM / 256);          // 32
    constexpr int TN  = DIM / 256;                          // 4
    const int bid = (blockIdx.x & 7) * (TOT >> 3) + (blockIdx.x >> 3);  // XCD swizzle
    const int e = bid / TPE, tt = bid % TPE, tm = tt / TN, tn = tt % TN;

    const unsigned short* A = h   + ((size_t)e * CAP + tm * 256) * HID;
    const unsigned short* B = w2t + ((size_t)e * DIM + tn * 256) * HID;
    f32x4 acc[8][4];
    #pragma unroll
    for (int m = 0; m < 8; ++m)
        #pragma unroll
        for (int n = 0; n < 4; ++n) acc[m][n] = (f32x4){0.f, 0.f, 0.f, 0.f};

    mainloop256<HID>(A, B, lds, acc);

    const int l = threadIdx.x & 63, w = threadIdx.x >> 6;
    const int l16 = l & 15, kh4 = l >> 4;
    const int wm = w >> 2, wn = w & 3;
    const float* b2e = b2 + (size_t)e * DIM + tn * 256;
    float bias[4];
    #pragma unroll
    for (int n = 0; n < 4; ++n) bias[n] = b2e[wn * 64 + n * 16 + l16];
    #pragma unroll
    for (int m = 0; m < 8; ++m)
        #pragma unroll
        for (int r = 0; r < 4; ++r) {
            int row = wm * 128 + m * 16 + kh4 * 4 + r;
            int slot = e * CAP + tm * 256 + row;
            int tok = slot_token[slot];
            if (tok >= 0) {
                float g = slot_gate[slot];
                #pragma unroll
                for (int n = 0; n < 4; ++n) {
                    int col = wn * 64 + n * 16 + l16;
                    float v = acc[m][n][r] + bias[n];
                    atomicAdd(out + (size_t)tok * DIM + tn * 256 + col, v * g);
                }
            }
        }
}

// ---------------------------------------------------------------------------
extern "C" void kernel_launch(void* const* d_in, const int* in_sizes, int n_in,
                              void* d_out, int out_size, void* d_ws, size_t ws_size,
                              hipStream_t stream) {
    (void)in_sizes; (void)n_in; (void)out_size; (void)ws_size;
    const float* x  = (const float*)d_in[0];
    const float* wg = (const float*)d_in[1];
    const float* w1 = (const float*)d_in[2];
    const float* b1 = (const float*)d_in[3];
    const float* w2 = (const float*)d_in[4];
    const float* b2 = (const float*)d_in[5];
    float* out = (float*)d_out;

    char* ws = (char*)d_ws;
    size_t off = 0;
    unsigned short* w1t  = (unsigned short*)(ws + off); off += (size_t)NEXP * HID * DIM * 2;  // 64 MB
    unsigned short* w2t  = (unsigned short*)(ws + off); off += (size_t)NEXP * DIM * HID * 2;  // 64 MB
    unsigned short* disp = (unsigned short*)(ws + off); off += (size_t)NEXP * CAP * DIM * 2;  // 32 MB
    unsigned short* hbuf = (unsigned short*)(ws + off); off += (size_t)NEXP * CAP * HID * 2;  // 128 MB
    int*   slot_token = (int*)  (ws + off); off += (size_t)NEXP * CAP * 4;
    float* slot_gate  = (float*)(ws + off); off += (size_t)NEXP * CAP * 4;
    int*   tok_e      = (int*)  (ws + off); off += (size_t)N_TOK * 2 * 4;
    float* tok_g      = (float*)(ws + off); off += (size_t)N_TOK * 2 * 4;

    // raise dynamic-LDS cap for the 128 KiB GEMM kernels (idempotent)
    hipFuncSetAttribute((const void*)gemm1_kernel,
                        hipFuncAttributeMaxDynamicSharedMemorySize, 131072);
    hipFuncSetAttribute((const void*)gemm2_kernel,
                        hipFuncAttributeMaxDynamicSharedMemorySize, 131072);

    hipLaunchKernelGGL(init_kernel, dim3(N_TOK * DIM / 4 / 256), dim3(256), 0, stream,
                       out, slot_token, slot_gate);
    hipLaunchKernelGGL(transpose_convert_kernel, dim3(HID / 32, DIM / 32, NEXP), dim3(256), 0, stream,
                       w1, w1t, DIM, HID);
    hipLaunchKernelGGL(transpose_convert_kernel, dim3(DIM / 32, HID / 32, NEXP), dim3(256), 0, stream,
                       w2, w2t, HID, DIM);
    hipLaunchKernelGGL(gate_kernel, dim3(N_TOK / 4), dim3(256), 0, stream, x, wg, tok_e, tok_g);
    hipLaunchKernelGGL(route_kernel, dim3(1), dim3(512), 0, stream,
                       tok_e, tok_g, slot_token, slot_gate);
    hipLaunchKernelGGL(dispatch_kernel, dim3(NEXP * CAP), dim3(256), 0, stream,
                       x, slot_token, disp);
    hipLaunchKernelGGL(gemm1_kernel, dim3((CAP / 256) * (HID / 256) * NEXP), dim3(512), 131072, stream,
                       disp, w1t, b1, hbuf);
    hipLaunchKernelGGL(gemm2_kernel, dim3((CAP / 256) * (DIM / 256) * NEXP), dim3(512), 131072, stream,
                       hbuf, w2t, b2, slot_token, slot_gate, out);
}

// Round 3
// 709.932 us; speedup vs baseline: 1.4111x; 1.1565x over previous
//
#include <hip/hip_runtime.h>
#include <hip/hip_bf16.h>
#include <math.h>

// Problem constants (fixed by reference setup_inputs)
#define N_TOK 8192   // B*S = 4*2048
#define DIM   1024   // D
#define HID   4096   // H
#define NEXP  8      // E
#define CAP   2048   // ceil(1.0 * 2 * 8192 / 8)

typedef short bf16x8 __attribute__((ext_vector_type(8)));
typedef float f32x4  __attribute__((ext_vector_type(4)));

__device__ __forceinline__ unsigned short f2bf(float f) {
    union { float f; unsigned u; } v; v.f = f;
    unsigned r = v.u;
    unsigned lsb = (r >> 16) & 1u;
    r += 0x7fffu + lsb;          // round-to-nearest-even on bf16 boundary
    return (unsigned short)(r >> 16);
}

// Branch-free exact-enough GELU: erf via Abramowitz-Stegun 7.1.26 (|err|<=1.5e-7).
// ~15 VALU ops, no divergence — replaces ocml erff (~70 ops, divergent 2-path).
__device__ __forceinline__ float gelu_f(float v) {
    float az = fabsf(v);
    float z  = az * 0.70710678118654752f;                 // |v|/sqrt(2), z >= 0
    float t  = __builtin_amdgcn_rcpf(fmaf(0.3275911f, z, 1.0f));
    float p  = fmaf(fmaf(fmaf(fmaf(1.061405429f, t, -1.453152027f),
                               t, 1.421413741f), t, -0.284496736f), t, 0.254829592f) * t;
    float ez = __expf(-z * z);                            // v_mul + v_exp
    float q5 = 0.5f * p * ez;                             // 0.5*(1-erf(z))
    float phi = (v >= 0.f) ? (1.f - q5) : q5;             // v_cndmask
    return v * phi;
}

// ---------------------------------------------------------------------------
// init: invalidate slot->token map (out no longer needs zeroing: combine
// overwrites every element)
// ---------------------------------------------------------------------------
__global__ __launch_bounds__(256) void init_kernel(int* __restrict__ slot_token) {
    int gid = blockIdx.x * 256 + threadIdx.x;
    slot_token[gid] = -1;
}

// ---------------------------------------------------------------------------
// transpose + fp32->bf16 convert:  in fp32 [E][R][C]  ->  out bf16 [E][C][R]
// 64x64 tile, float4 reads, ushort4 (8B) writes -> 128B store segments.
// ---------------------------------------------------------------------------
__global__ __launch_bounds__(256) void transpose_convert_kernel(
        const float* __restrict__ in, unsigned short* __restrict__ outp,
        int R, int C) {
    int e  = blockIdx.z;
    int c0 = blockIdx.x * 64, r0 = blockIdx.y * 64;
    __shared__ float tile[64][65];
    const float* ip = in + (size_t)e * R * C;
    unsigned short* op = outp + (size_t)e * R * C;
    int t = threadIdx.x;
    int rr = t >> 4, cc = (t & 15) * 4;
    #pragma unroll
    for (int p = 0; p < 4; ++p) {
        f32x4 v = *(const f32x4*)(ip + (size_t)(r0 + p * 16 + rr) * C + c0 + cc);
        tile[p * 16 + rr][cc + 0] = v[0];
        tile[p * 16 + rr][cc + 1] = v[1];
        tile[p * 16 + rr][cc + 2] = v[2];
        tile[p * 16 + rr][cc + 3] = v[3];
    }
    __syncthreads();
    int ct = t >> 4, rq = (t & 15) * 4;
    #pragma unroll
    for (int p = 0; p < 4; ++p) {
        int c = p * 16 + ct;
        ushort4 o;
        o.x = f2bf(tile[rq + 0][c]);
        o.y = f2bf(tile[rq + 1][c]);
        o.z = f2bf(tile[rq + 2][c]);
        o.w = f2bf(tile[rq + 3][c]);
        *(ushort4*)(op + (size_t)(c0 + c) * R + r0 + rq) = o;
    }
}

// ---------------------------------------------------------------------------
// gate: one wave per token. fp32 logits, softmax, top-2, normalized gates.
// ---------------------------------------------------------------------------
__global__ __launch_bounds__(256) void gate_kernel(
        const float* __restrict__ x, const float* __restrict__ wg,
        int* __restrict__ tok_e, float* __restrict__ tok_g) {
    int wave = threadIdx.x >> 6, lane = threadIdx.x & 63;
    int n = blockIdx.x * 4 + wave;
    const float* xr = x + (size_t)n * DIM;
    float acc[8];
    #pragma unroll
    for (int e = 0; e < 8; ++e) acc[e] = 0.f;
    for (int j = 0; j < DIM / 64; ++j) {
        int d = lane + 64 * j;
        float xv = xr[d];
        const f32x4* wr = (const f32x4*)(wg + (size_t)d * 8);
        f32x4 w0 = wr[0], w1 = wr[1];
        acc[0] += xv * w0[0]; acc[1] += xv * w0[1];
        acc[2] += xv * w0[2]; acc[3] += xv * w0[3];
        acc[4] += xv * w1[0]; acc[5] += xv * w1[1];
        acc[6] += xv * w1[2]; acc[7] += xv * w1[3];
    }
    #pragma unroll
    for (int off = 32; off > 0; off >>= 1) {
        #pragma unroll
        for (int e = 0; e < 8; ++e) acc[e] += __shfl_down(acc[e], off);
    }
    if (lane == 0) {
        float mx = acc[0];
        #pragma unroll
        for (int e = 1; e < 8; ++e) mx = fmaxf(mx, acc[e]);
        float p[8], s = 0.f;
        #pragma unroll
        for (int e = 0; e < 8; ++e) { p[e] = expf(acc[e] - mx); s += p[e]; }
        int i0 = 0;
        #pragma unroll
        for (int e = 1; e < 8; ++e) if (acc[e] > acc[i0]) i0 = e;
        int i1 = (i0 == 0) ? 1 : 0;
        #pragma unroll
        for (int e = 0; e < 8; ++e) if (e != i0 && acc[e] > acc[i1]) i1 = e;
        float g0 = p[i0] / s, g1 = p[i1] / s;
        float gs = fmaxf(g0 + g1, 1e-9f);
        tok_e[n * 2 + 0] = i0;  tok_e[n * 2 + 1] = i1;
        tok_g[n * 2 + 0] = g0 / gs;  tok_g[n * 2 + 1] = g1 / gs;
    }
}

// ---------------------------------------------------------------------------
// route: GShard capacity positions. 1 block, 8 waves; wave w owns expert w.
// Emits slot->token (for dispatch) AND token->slot (for combine).
// ---------------------------------------------------------------------------
__global__ __launch_bounds__(512) void route_kernel(
        const int* __restrict__ tok_e,
        int* __restrict__ slot_token, int* __restrict__ tok_slot) {
    __shared__ int te[N_TOK];      // 32 KB
    int w = threadIdx.x >> 6;      // expert id
    int lane = threadIdx.x & 63;
    unsigned long long below = (lane == 63) ? 0x7fffffffffffffffull
                                            : ((1ull << lane) - 1ull);
    int cnt = 0;
    for (int kk = 0; kk < 2; ++kk) {
        __syncthreads();
        for (int i = threadIdx.x; i < N_TOK; i += 512) te[i] = tok_e[i * 2 + kk];
        __syncthreads();
        #pragma unroll 4
        for (int base = 0; base < N_TOK; base += 64) {
            int n = base + lane;
            bool mine = (te[n] == w);
            unsigned long long m = __ballot(mine);
            if (mine) {
                int pos = cnt + __popcll(m & below);
                bool ok = pos < CAP;
                tok_slot[n * 2 + kk] = ok ? (w * CAP + pos) : -1;
                if (ok) slot_token[w * CAP + pos] = n;
            }
            cnt += __popcll(m);
        }
    }
}

// ---------------------------------------------------------------------------
// dispatch: gather token rows into bf16 disp[E*CAP][DIM]; zero empty slots
// ---------------------------------------------------------------------------
__global__ __launch_bounds__(256) void dispatch_kernel(
        const float* __restrict__ x, const int* __restrict__ slot_token,
        unsigned short* __restrict__ disp) {
    int s = blockIdx.x;
    int tok = slot_token[s];
    int t = threadIdx.x;
    unsigned short* dp = disp + (size_t)s * DIM + t * 4;
    uint2 o;
    if (tok < 0) { o.x = 0u; o.y = 0u; }
    else {
        const f32x4 v = *(const f32x4*)(x + (size_t)tok * DIM + t * 4);
        o.x = (unsigned)f2bf(v[0]) | ((unsigned)f2bf(v[1]) << 16);
        o.y = (unsigned)f2bf(v[2]) | ((unsigned)f2bf(v[3]) << 16);
    }
    *(uint2*)dp = o;
}

// ---------------------------------------------------------------------------
// 256x256 8-phase GEMM core (unchanged from round 2 — isolating epilogue fix):
//   BM=BN=256, BK=64, 512 threads = 8 waves (2M x 4N), per-wave C = 128x64.
//   Stripe-transposed LDS (zero bank conflicts, verified), counted vmcnt(4),
//   setprio(1) around MFMA clusters.
// ---------------------------------------------------------------------------
template<int KD>
__device__ __forceinline__ void mainloop256(
        const unsigned short* __restrict__ Ag, const unsigned short* __restrict__ Bg,
        unsigned short* lds, f32x4 (&acc)[8][4]) {
    const int t = threadIdx.x;
    const int w = t >> 6, l = t & 63;
    const int wm = w >> 2, wn = w & 3;

    const int slot0 = w * 64 + l;
    const int slot1 = 512 + w * 64 + l;
    const int r0 = (slot0 >> 6) * 16 + (slot0 & 15), c0 = (slot0 >> 4) & 3;
    const int r1 = (slot1 >> 6) * 16 + (slot1 & 15), c1 = (slot1 >> 4) & 3;
    const size_t ofs0 = (size_t)r0 * KD + c0 * 8;
    const size_t ofs1 = (size_t)r1 * KD + c1 * 8;
    const int dst0 = (w * 64) * 8;
    const int dst1 = (512 + w * 64) * 8;

    auto stage = [&](const unsigned short* G, int ldsbase, int kh, int kt) {
        __builtin_amdgcn_global_load_lds(
            (const __attribute__((address_space(1))) void*)(G + ofs0 + kt + kh * 32),
            (__attribute__((address_space(3))) void*)(lds + ldsbase + kh * 8192 + dst0), 16, 0, 0);
        __builtin_amdgcn_global_load_lds(
            (const __attribute__((address_space(1))) void*)(G + ofs1 + kt + kh * 32),
            (__attribute__((address_space(3))) void*)(lds + ldsbase + kh * 8192 + dst1), 16, 0, 0);
    };
    auto ldA = [&](int abase, int ks, int m) {
        return *(const bf16x8*)(lds + abase + ks * 8192 + (wm * 8 + m) * 512 + l * 8);
    };
    auto ldB = [&](int bbase, int ks, int n) {
        return *(const bf16x8*)(lds + bbase + ks * 8192 + (wn * 4 + n) * 512 + l * 8);
    };

#define MFMA_PAIR(nlo)                                                                     \
    __builtin_amdgcn_s_setprio(1);                                                         \
    _Pragma("unroll")                                                                      \
    for (int m = 0; m < 8; ++m) {                                                          \
        acc[m][nlo]     = __builtin_amdgcn_mfma_f32_16x16x32_bf16(af[m], bf[nlo],     acc[m][nlo],     0, 0, 0); \
        acc[m][nlo + 1] = __builtin_amdgcn_mfma_f32_16x16x32_bf16(af[m], bf[nlo + 1], acc[m][nlo + 1], 0, 0, 0); \
    }                                                                                      \
    __builtin_amdgcn_s_setprio(0);

    constexpr int NT = KD / 64;
    bf16x8 af[8], bf[4];

    stage(Ag, 0, 0, 0);  stage(Bg, 16384, 0, 0);
    stage(Ag, 0, 1, 0);  stage(Bg, 16384, 1, 0);

    int cur = 0;
#pragma unroll 1
    for (int T = 0; T < NT; ++T, cur ^= 1) {
        const int abase = cur * 32768, bbase = abase + 16384;
        const int nA = (cur ^ 1) * 32768, nB = nA + 16384;
        const int ktn = (T + 1) * 64;
        const bool pf = (T + 1 < NT);

        asm volatile("s_waitcnt vmcnt(4)\n\ts_barrier" ::: "memory");
        #pragma unroll
        for (int m = 0; m < 8; ++m) af[m] = ldA(abase, 0, m);
        bf[0] = ldB(bbase, 0, 0);  bf[1] = ldB(bbase, 0, 1);
        if (pf) stage(Ag, nA, 0, ktn);
        MFMA_PAIR(0)
        bf[2] = ldB(bbase, 0, 2);  bf[3] = ldB(bbase, 0, 3);
        if (pf) stage(Bg, nB, 0, ktn);
        MFMA_PAIR(2)
        if (pf) { asm volatile("s_waitcnt vmcnt(4)\n\ts_barrier" ::: "memory"); }
        else    { asm volatile("s_waitcnt vmcnt(0)\n\ts_barrier" ::: "memory"); }
        #pragma unroll
        for (int m = 0; m < 8; ++m) af[m] = ldA(abase, 1, m);
        bf[0] = ldB(bbase, 1, 0);  bf[1] = ldB(bbase, 1, 1);
        if (pf) stage(Ag, nA, 1, ktn);
        MFMA_PAIR(0)
        bf[2] = ldB(bbase, 1, 2);  bf[3] = ldB(bbase, 1, 3);
        if (pf) stage(Bg, nB, 1, ktn);
        MFMA_PAIR(2)
    }
#undef MFMA_PAIR
}

// GEMM1: h[e] = gelu(disp[e] @ w1[e] + b1[e]),  M=CAP, N=HID, K=DIM
__global__ __launch_bounds__(512, 2) void gemm1_kernel(
        const unsigned short* __restrict__ disp, const unsigned short* __restrict__ w1t,
        const float* __restrict__ b1, unsigned short* __restrict__ h) {
    extern __shared__ unsigned short lds[];
    constexpr int TOT = (CAP / 256) * (HID / 256) * NEXP;   // 1024
    constexpr int TPE = (CAP / 256) * (HID / 256);          // 128
    constexpr int TN  = HID / 256;                          // 16
    const int bid = (blockIdx.x & 7) * (TOT >> 3) + (blockIdx.x >> 3);  // XCD swizzle
    const int e = bid / TPE, tt = bid % TPE, tm = tt / TN, tn = tt % TN;

    const unsigned short* A = disp + ((size_t)e * CAP + tm * 256) * DIM;
    const unsigned short* B = w1t  + ((size_t)e * HID + tn * 256) * DIM;
    f32x4 acc[8][4];
    #pragma unroll
    for (int m = 0; m < 8; ++m)
        #pragma unroll
        for (int n = 0; n < 4; ++n) acc[m][n] = (f32x4){0.f, 0.f, 0.f, 0.f};

    mainloop256<DIM>(A, B, lds, acc);

    const int l = threadIdx.x & 63, w = threadIdx.x >> 6;
    const int l16 = l & 15, kh4 = l >> 4;
    const int wm = w >> 2, wn = w & 3;
    const float* b1e = b1 + (size_t)e * HID + tn * 256;
    float bias[4];
    #pragma unroll
    for (int n = 0; n < 4; ++n) bias[n] = b1e[wn * 64 + n * 16 + l16];
    unsigned short* H = h + ((size_t)e * CAP + tm * 256) * HID + tn * 256;
    #pragma unroll
    for (int m = 0; m < 8; ++m)
        #pragma unroll
        for (int n = 0; n < 4; ++n)
            #pragma unroll
            for (int r = 0; r < 4; ++r) {
                int row = wm * 128 + m * 16 + kh4 * 4 + r;   // C/D: row=(lane>>4)*4+reg
                int col = wn * 64 + n * 16 + l16;            //      col=lane&15
                H[(size_t)row * HID + col] = f2bf(gelu_f(acc[m][n][r] + bias[n]));
            }
}

// GEMM2: y[e] = h[e] @ w2[e] + b2[e] -> plain f32 stores (no atomics)
__global__ __launch_bounds__(512, 2) void gemm2_kernel(
        const unsigned short* __restrict__ h, const unsigned short* __restrict__ w2t,
        const float* __restrict__ b2, float* __restrict__ y) {
    extern __shared__ unsigned short lds[];
    constexpr int TOT = (CAP / 256) * (DIM / 256) * NEXP;   // 256
    constexpr int TPE = (CAP / 256) * (DIM / 256);          // 32
    constexpr int TN  = DIM / 256;                          // 4
    const int bid = (blockIdx.x & 7) * (TOT >> 3) + (blockIdx.x >> 3);  // XCD swizzle
    const int e = bid / TPE, tt = bid % TPE, tm = tt / TN, tn = tt % TN;

    const unsigned short* A = h   + ((size_t)e * CAP + tm * 256) * HID;
    const unsigned short* B = w2t + ((size_t)e * DIM + tn * 256) * HID;
    f32x4 acc[8][4];
    #pragma unroll
    for (int m = 0; m < 8; ++m)
        #pragma unroll
        for (int n = 0; n < 4; ++n) acc[m][n] = (f32x4){0.f, 0.f, 0.f, 0.f};

    mainloop256<HID>(A, B, lds, acc);

    const int l = threadIdx.x & 63, w = threadIdx.x >> 6;
    const int l16 = l & 15, kh4 = l >> 4;
    const int wm = w >> 2, wn = w & 3;
    const float* b2e = b2 + (size_t)e * DIM + tn * 256;
    float bias[4];
    #pragma unroll
    for (int n = 0; n < 4; ++n) bias[n] = b2e[wn * 64 + n * 16 + l16];
    float* Y = y + ((size_t)e * CAP + tm * 256) * DIM + tn * 256;
    #pragma unroll
    for (int m = 0; m < 8; ++m)
        #pragma unroll
        for (int n = 0; n < 4; ++n)
            #pragma unroll
            for (int r = 0; r < 4; ++r) {
                int row = wm * 128 + m * 16 + kh4 * 4 + r;
                int col = wn * 64 + n * 16 + l16;
                Y[(size_t)row * DIM + col] = acc[m][n][r] + bias[n];
            }
}

// ---------------------------------------------------------------------------
// combine: out[n] = g0*y[slot0] + g1*y[slot1]  (gather, no atomics;
// writes every output element -> out needs no zero-init)
// ---------------------------------------------------------------------------
__global__ __launch_bounds__(256) void combine_kernel(
        const float* __restrict__ y, const int* __restrict__ tok_slot,
        const float* __restrict__ tok_g, float* __restrict__ out) {
    int n = blockIdx.x, t = threadIdx.x;
    int s0 = tok_slot[n * 2], s1 = tok_slot[n * 2 + 1];
    float g0 = tok_g[n * 2], g1 = tok_g[n * 2 + 1];
    f32x4 r = {0.f, 0.f, 0.f, 0.f};
    if (s0 >= 0) {
        f32x4 v = *(const f32x4*)(y + (size_t)s0 * DIM + t * 4);
        r[0] = g0 * v[0]; r[1] = g0 * v[1]; r[2] = g0 * v[2]; r[3] = g0 * v[3];
    }
    if (s1 >= 0) {
        f32x4 v = *(const f32x4*)(y + (size_t)s1 * DIM + t * 4);
        r[0] += g1 * v[0]; r[1] += g1 * v[1]; r[2] += g1 * v[2]; r[3] += g1 * v[3];
    }
    *(f32x4*)(out + (size_t)n * DIM + t * 4) = r;
}

// ---------------------------------------------------------------------------
extern "C" void kernel_launch(void* const* d_in, const int* in_sizes, int n_in,
                              void* d_out, int out_size, void* d_ws, size_t ws_size,
                              hipStream_t stream) {
    (void)in_sizes; (void)n_in; (void)out_size; (void)ws_size;
    const float* x  = (const float*)d_in[0];
    const float* wg = (const float*)d_in[1];
    const float* w1 = (const float*)d_in[2];
    const float* b1 = (const float*)d_in[3];
    const float* w2 = (const float*)d_in[4];
    const float* b2 = (const float*)d_in[5];
    float* out = (float*)d_out;

    char* ws = (char*)d_ws;
    size_t off = 0;
    unsigned short* w1t  = (unsigned short*)(ws + off); off += (size_t)NEXP * HID * DIM * 2;  // 64 MB
    unsigned short* w2t  = (unsigned short*)(ws + off); off += (size_t)NEXP * DIM * HID * 2;  // 64 MB
    unsigned short* disp = (unsigned short*)(ws + off); off += (size_t)NEXP * CAP * DIM * 2;  // 32 MB
    unsigned short* hbuf = (unsigned short*)(ws + off); off += (size_t)NEXP * CAP * HID * 2;  // 128 MB
    int*   slot_token = (int*)  (ws + off); off += (size_t)NEXP * CAP * 4;
    int*   tok_e      = (int*)  (ws + off); off += (size_t)N_TOK * 2 * 4;
    float* tok_g      = (float*)(ws + off); off += (size_t)N_TOK * 2 * 4;
    int*   tok_slot   = (int*)  (ws + off); off += (size_t)N_TOK * 2 * 4;
    float* ybuf = (float*)w1t;   // w1t (64 MB) is dead after gemm1; exact fit for
                                 // f32 y[E*CAP][DIM] = 16384*1024*4 = 64 MB

    hipFuncSetAttribute((const void*)gemm1_kernel,
                        hipFuncAttributeMaxDynamicSharedMemorySize, 131072);
    hipFuncSetAttribute((const void*)gemm2_kernel,
                        hipFuncAttributeMaxDynamicSharedMemorySize, 131072);

    hipLaunchKernelGGL(init_kernel, dim3(NEXP * CAP / 256), dim3(256), 0, stream,
                       slot_token);
    hipLaunchKernelGGL(transpose_convert_kernel, dim3(HID / 64, DIM / 64, NEXP), dim3(256), 0, stream,
                       w1, w1t, DIM, HID);
    hipLaunchKernelGGL(transpose_convert_kernel, dim3(DIM / 64, HID / 64, NEXP), dim3(256), 0, stream,
                       w2, w2t, HID, DIM);
    hipLaunchKernelGGL(gate_kernel, dim3(N_TOK / 4), dim3(256), 0, stream, x, wg, tok_e, tok_g);
    hipLaunchKernelGGL(route_kernel, dim3(1), dim3(512), 0, stream,
                       tok_e, slot_token, tok_slot);
    hipLaunchKernelGGL(dispatch_kernel, dim3(NEXP * CAP), dim3(256), 0, stream,
                       x, slot_token, disp);
    hipLaunchKernelGGL(gemm1_kernel, dim3((CAP / 256) * (HID / 256) * NEXP), dim3(512), 131072, stream,
                       disp, w1t, b1, hbuf);
    hipLaunchKernelGGL(gemm2_kernel, dim3((CAP / 256) * (DIM / 256) * NEXP), dim3(512), 131072, stream,
                       hbuf, w2t, b2, ybuf);
    hipLaunchKernelGGL(combine_kernel, dim3(N_TOK), dim3(256), 0, stream,
                       ybuf, tok_slot, tok_g, out);
}